// Round 1
// baseline (13523.177 us; speedup 1.0000x reference)
//
#include <hip/hip_runtime.h>
#include <cmath>

namespace {
constexpr int Vv  = 10000;
constexpr int Ee  = 512;
constexpr int Hh  = 1024;
constexpr int Bb  = 128;
constexpr int Tt  = 64;
constexpr int CTX = 4096;
constexpr int Gg  = 4096;   // 4*H
constexpr int KIN1 = 4608;  // E + CTX
constexpr int KC = 32;      // K chunk
constexpr int BM = 32;      // batch tile
constexpr int BN = 64;      // column tile (4 gates x 16 h for LSTM kernels)
}

// Tiled fp32 GEMM segment: acc[2][4] += A[b0+..][k] * W[row(r)][coloff+k]
// Tile: BM=32 batch rows x BN=64 W-rows. 256 threads; thread computes 2b x 4j.
// W-row map: row(r) = rowbase + (r>>4)*rowstride + (r&15)
//   (rowstride=16 -> rows rowbase+r contiguous; rowstride=H -> 4 gate blocks)
__device__ __forceinline__ void gemm_seg(
    const float* __restrict__ A, int lda, int b0,
    const float* __restrict__ W, int ldw, int coloff,
    int rowbase, int rowstride, int nrows, int K,
    float acc[2][4], float (*As)[BM + 2], float (*Ws)[BN + 4], int tid)
{
  const int jq  = tid & 15;        // j quad
  const int bbq = tid >> 4;        // b pair
  const int arow = tid >> 3, akq = tid & 7;   // A staging: 32 rows x 8 float4
  const int wr0 = tid >> 3, wkq = tid & 7;    // W staging: 64 rows x 8 float4 (2 rows/thread)
  const int wr1 = wr0 + 32;
  const int grow0 = rowbase + (wr0 >> 4) * rowstride + (wr0 & 15);
  const int grow1 = rowbase + (wr1 >> 4) * rowstride + (wr1 & 15);
  const float* aptr  = A + (size_t)(b0 + arow) * lda + akq * 4;
  const float* wptr0 = (grow0 < nrows) ? (W + (size_t)grow0 * ldw + coloff + wkq * 4) : nullptr;
  const float* wptr1 = (grow1 < nrows) ? (W + (size_t)grow1 * ldw + coloff + wkq * 4) : nullptr;

  // software prefetch of chunk 0 into registers
  float4 ar = *(const float4*)aptr;
  float4 w0 = wptr0 ? *(const float4*)wptr0 : float4{0.f, 0.f, 0.f, 0.f};
  float4 w1 = wptr1 ? *(const float4*)wptr1 : float4{0.f, 0.f, 0.f, 0.f};

  for (int k0 = 0; k0 < K; k0 += KC) {
    __syncthreads();   // prior compute done -> LDS safe to overwrite
    As[akq * 4 + 0][arow] = ar.x; As[akq * 4 + 1][arow] = ar.y;
    As[akq * 4 + 2][arow] = ar.z; As[akq * 4 + 3][arow] = ar.w;
    Ws[wkq * 4 + 0][wr0] = w0.x; Ws[wkq * 4 + 1][wr0] = w0.y;
    Ws[wkq * 4 + 2][wr0] = w0.z; Ws[wkq * 4 + 3][wr0] = w0.w;
    Ws[wkq * 4 + 0][wr1] = w1.x; Ws[wkq * 4 + 1][wr1] = w1.y;
    Ws[wkq * 4 + 2][wr1] = w1.z; Ws[wkq * 4 + 3][wr1] = w1.w;
    __syncthreads();
    const int kn = k0 + KC;
    if (kn < K) {      // prefetch next chunk; overlaps the compute below
      ar = *(const float4*)(aptr + kn);
      w0 = wptr0 ? *(const float4*)(wptr0 + kn) : float4{0.f, 0.f, 0.f, 0.f};
      w1 = wptr1 ? *(const float4*)(wptr1 + kn) : float4{0.f, 0.f, 0.f, 0.f};
    }
#pragma unroll
    for (int kk = 0; kk < KC; ++kk) {
      const float a0 = As[kk][2 * bbq];
      const float a1 = As[kk][2 * bbq + 1];
      const float4 wv = *(const float4*)&Ws[kk][jq * 4];
      acc[0][0] = fmaf(a0, wv.x, acc[0][0]);
      acc[0][1] = fmaf(a0, wv.y, acc[0][1]);
      acc[0][2] = fmaf(a0, wv.z, acc[0][2]);
      acc[0][3] = fmaf(a0, wv.w, acc[0][3]);
      acc[1][0] = fmaf(a1, wv.x, acc[1][0]);
      acc[1][1] = fmaf(a1, wv.y, acc[1][1]);
      acc[1][2] = fmaf(a1, wv.z, acc[1][2]);
      acc[1][3] = fmaf(a1, wv.w, acc[1][3]);
    }
  }
}

// init: zero h1(x2), h2(x2), c1, c2 (contiguous 6*B*H) and gather x0 = drop*emb[data[:,0]]
__global__ __launch_bounds__(256) void init_kernel(
    const int* __restrict__ data, const float* __restrict__ drop,
    const float* __restrict__ embW, float* __restrict__ zbuf, float* __restrict__ xcur)
{
  const int i = blockIdx.x * 256 + threadIdx.x;
  if (i < 6 * Bb * Hh) zbuf[i] = 0.f;
  if (i < Bb * Ee) {
    const int b = i >> 9, e = i & 511;
    const int idx = data[b * Tt];
    xcur[i] = drop[idx] * embW[(size_t)idx * Ee + e];
  }
}

// base1[b][j] = b_ih1[j] + b_hh1[j] + sum_k h_n[b][k] * W_ih1[j][512+k]   (once)
__global__ __launch_bounds__(256) void base1_kernel(
    const float* __restrict__ h_n, const float* __restrict__ W_ih1,
    const float* __restrict__ b_ih1, const float* __restrict__ b_hh1,
    float* __restrict__ base1)
{
  __shared__ float As[KC][BM + 2];
  __shared__ float Ws[KC][BN + 4];
  const int tid = threadIdx.x;
  const int j0 = blockIdx.x * BN;
  const int b0 = blockIdx.y * BM;
  float acc[2][4] = {{0.f, 0.f, 0.f, 0.f}, {0.f, 0.f, 0.f, 0.f}};
  gemm_seg(h_n, CTX, b0, W_ih1, KIN1, Ee, j0, 16, Gg, CTX, acc, As, Ws, tid);
  const int jq = tid & 15, bbq = tid >> 4;
  const int j = j0 + jq * 4;
#pragma unroll
  for (int v = 0; v < 2; ++v) {
    const int bg = b0 + 2 * bbq + v;
#pragma unroll
    for (int u = 0; u < 4; ++u)
      base1[(size_t)bg * Gg + j + u] = acc[v][u] + b_ih1[j + u] + b_hh1[j + u];
  }
}

// One LSTM layer step: gates = base + A1*W1^T + A2*W2^T -> cell -> h_out, c_io
// Block tile: 32 batch x 16 h (x 4 gates).
__global__ __launch_bounds__(256) void lstm_kernel(
    const float* __restrict__ A1, int lda1,
    const float* __restrict__ W1, int ldw1, int coloff1, int K1,
    const float* __restrict__ A2, int lda2,
    const float* __restrict__ W2, int ldw2, int K2,
    const float* __restrict__ base_mat,                       // B x G (layer1) or null
    const float* __restrict__ bias_a, const float* __restrict__ bias_b, // layer2 biases or null
    float* __restrict__ h_out, float* __restrict__ c_io)
{
  __shared__ float As[KC][BM + 2];
  __shared__ float Ws[KC][BN + 4];
  __shared__ float gsm[BM][BN + 1];
  const int tid = threadIdx.x;
  const int h0 = blockIdx.x * 16;
  const int b0 = blockIdx.y * BM;
  float acc[2][4] = {{0.f, 0.f, 0.f, 0.f}, {0.f, 0.f, 0.f, 0.f}};
  gemm_seg(A1, lda1, b0, W1, ldw1, coloff1, h0, Hh, Gg, K1, acc, As, Ws, tid);
  gemm_seg(A2, lda2, b0, W2, ldw2, 0,       h0, Hh, Gg, K2, acc, As, Ws, tid);
  // park gates in LDS so each (b,h) cell sees its i/f/g/o
  {
    const int jq = tid & 15, bbq = tid >> 4;
#pragma unroll
    for (int u = 0; u < 4; ++u) {
      gsm[2 * bbq][jq * 4 + u]     = acc[0][u];
      gsm[2 * bbq + 1][jq * 4 + u] = acc[1][u];
    }
  }
  __syncthreads();
#pragma unroll
  for (int p = tid; p < BM * 16; p += 256) {
    const int bl = p >> 4, lh = p & 15;
    const int bg = b0 + bl, hg = h0 + lh;
    float vi = gsm[bl][lh];
    float vf = gsm[bl][16 + lh];
    float vg = gsm[bl][32 + lh];
    float vo = gsm[bl][48 + lh];
    if (base_mat) {
      const float* bp = base_mat + (size_t)bg * Gg + hg;
      vi += bp[0]; vf += bp[Hh]; vg += bp[2 * Hh]; vo += bp[3 * Hh];
    } else {
      vi += bias_a[hg] + bias_b[hg];
      vf += bias_a[Hh + hg] + bias_b[Hh + hg];
      vg += bias_a[2 * Hh + hg] + bias_b[2 * Hh + hg];
      vo += bias_a[3 * Hh + hg] + bias_b[3 * Hh + hg];
    }
    const float si = 1.f / (1.f + expf(-vi));
    const float sf = 1.f / (1.f + expf(-vf));
    const float so = 1.f / (1.f + expf(-vo));
    const float tg = tanhf(vg);
    const size_t idx = (size_t)bg * Hh + hg;
    const float cn = sf * c_io[idx] + si * tg;
    c_io[idx] = cn;
    h_out[idx] = so * tanhf(cn);
  }
}

// logits tile: out[b][j] = h2[b]·W_out[j] + b_out[j]
__global__ __launch_bounds__(256) void logits_kernel(
    const float* __restrict__ h2,
    const float* __restrict__ W_out, const float* __restrict__ b_out,
    float* __restrict__ outp)
{
  __shared__ float As[KC][BM + 2];
  __shared__ float Ws[KC][BN + 4];
  const int tid = threadIdx.x;
  const int j0 = blockIdx.x * BN;
  const int b0 = blockIdx.y * BM;
  float acc[2][4] = {{0.f, 0.f, 0.f, 0.f}, {0.f, 0.f, 0.f, 0.f}};
  gemm_seg(h2, Hh, b0, W_out, Hh, 0, j0, 16, Vv, Hh, acc, As, Ws, tid);
  const int jq = tid & 15, bbq = tid >> 4;
  const int j = j0 + jq * 4;
  if (j + 3 < Vv) {
    const float4 bo = *(const float4*)(b_out + j);
#pragma unroll
    for (int v = 0; v < 2; ++v) {
      const int bg = b0 + 2 * bbq + v;
      float4 s{acc[v][0] + bo.x, acc[v][1] + bo.y, acc[v][2] + bo.z, acc[v][3] + bo.w};
      *(float4*)(outp + (size_t)bg * Vv + j) = s;
    }
  } else {
#pragma unroll
    for (int v = 0; v < 2; ++v) {
      const int bg = b0 + 2 * bbq + v;
#pragma unroll
      for (int u = 0; u < 4; ++u)
        if (j + u < Vv) outp[(size_t)bg * Vv + j + u] = acc[v][u] + b_out[j + u];
    }
  }
}

// per-batch-row argmax (first-max ties, matching jnp.argmax) + next-input gather
__global__ __launch_bounds__(256) void argmax_kernel(
    const float* __restrict__ logits, const int* __restrict__ tf_mask_t,
    const int* __restrict__ data, int t,
    const float* __restrict__ drop, const float* __restrict__ embW,
    float* __restrict__ xcur)
{
  const int b = blockIdx.x;
  const int tid = threadIdx.x;
  const float* row = logits + (size_t)b * Vv;
  float best = -3.0e38f;
  int bi = 0;
  for (int j = tid; j < Vv; j += 256) {
    const float v = row[j];
    if (v > best) { best = v; bi = j; }   // strict > keeps first max within the stride
  }
  __shared__ float sv[256];
  __shared__ int si[256];
  sv[tid] = best; si[tid] = bi;
  __syncthreads();
  for (int s = 128; s > 0; s >>= 1) {
    if (tid < s) {
      const float v2 = sv[tid + s]; const int i2 = si[tid + s];
      if (v2 > sv[tid] || (v2 == sv[tid] && i2 < si[tid])) { sv[tid] = v2; si[tid] = i2; }
    }
    __syncthreads();
  }
  const int ind = si[0];
  const int mask = tf_mask_t[b];
  const int tfidx = data[b * Tt + t + 1];
  const float dm = drop[tfidx];
  for (int e = tid; e < Ee; e += 256) {
    // predicted path uses RAW emb_W (no drop mask); teacher-forced path uses masked emb
    xcur[(size_t)b * Ee + e] = (mask == 1) ? embW[(size_t)ind * Ee + e]
                                           : dm * embW[(size_t)tfidx * Ee + e];
  }
}

extern "C" void kernel_launch(void* const* d_in, const int* in_sizes, int n_in,
                              void* d_out, int out_size, void* d_ws, size_t ws_size,
                              hipStream_t stream) {
  (void)in_sizes; (void)n_in; (void)out_size; (void)ws_size;
  const float* h_n   = (const float*)d_in[0];
  const int*   data  = (const int*)d_in[1];
  const int*   tfm   = (const int*)d_in[2];
  const float* drop  = (const float*)d_in[3];
  const float* embW  = (const float*)d_in[4];
  const float* W_ih1 = (const float*)d_in[5];
  const float* W_hh1 = (const float*)d_in[6];
  const float* b_ih1 = (const float*)d_in[7];
  const float* b_hh1 = (const float*)d_in[8];
  const float* W_ih2 = (const float*)d_in[9];
  const float* W_hh2 = (const float*)d_in[10];
  const float* b_ih2 = (const float*)d_in[11];
  const float* b_hh2 = (const float*)d_in[12];
  const float* W_out = (const float*)d_in[13];
  const float* b_out = (const float*)d_in[14];
  float* out = (float*)d_out;

  // workspace layout (floats):
  // [h1 ping|h1 pong|h2 ping|h2 pong|c1|c2] (zeroed) | xcur | base1
  float* ws    = (float*)d_ws;
  float* h1buf = ws;                        // 2 * B*H
  float* h2buf = ws + 2 * Bb * Hh;          // 2 * B*H
  float* c1    = ws + 4 * Bb * Hh;
  float* c2    = ws + 5 * Bb * Hh;
  float* xcur  = ws + 6 * Bb * Hh;          // B*E
  float* base1 = xcur + Bb * Ee;            // B*G

  init_kernel<<<(6 * Bb * Hh) / 256, 256, 0, stream>>>(data, drop, embW, ws, xcur);
  base1_kernel<<<dim3(Gg / BN, Bb / BM), 256, 0, stream>>>(h_n, W_ih1, b_ih1, b_hh1, base1);

  for (int t = 0; t < Tt - 1; ++t) {
    float* h1p = h1buf + (t & 1) * (Bb * Hh);
    float* h1n = h1buf + ((t + 1) & 1) * (Bb * Hh);
    float* h2p = h2buf + (t & 1) * (Bb * Hh);
    float* h2n = h2buf + ((t + 1) & 1) * (Bb * Hh);

    // layer 1: x part of W_ih1 (cols 0..511) + recurrent W_hh1; h_n part folded into base1
    lstm_kernel<<<dim3(Hh / 16, Bb / BM), 256, 0, stream>>>(
        xcur, Ee, W_ih1, KIN1, 0, Ee,
        h1p, Hh, W_hh1, Hh, Hh,
        base1, nullptr, nullptr,
        h1n, c1);
    // layer 2
    lstm_kernel<<<dim3(Hh / 16, Bb / BM), 256, 0, stream>>>(
        h1n, Hh, W_ih2, Hh, 0, Hh,
        h2p, Hh, W_hh2, Hh, Hh,
        nullptr, b_ih2, b_hh2,
        h2n, c2);

    float* out_t = out + (size_t)t * Bb * Vv;
    logits_kernel<<<dim3((Vv + BN - 1) / BN, Bb / BM), 256, 0, stream>>>(h2n, W_out, b_out, out_t);
    argmax_kernel<<<Bb, 256, 0, stream>>>(out_t, tfm + t * Bb, data, t, drop, embW, xcur);
  }
}